// Round 19
// baseline (182.353 us; speedup 1.0000x reference)
//
#include <hip/hip_runtime.h>
#include <hip/hip_bf16.h>

#define B_SZ 8192
#define D_SZ 256
#define NTILES 2080   // (8192/128)*(8192/128+1)/2 upper-tri tiles
#define GRID_SIM 1024 // persistent, 4 blocks/CU (32 KB LDS, ~120 VGPR)
// rows pre-scaled by sqrt(log2(e)/T): exp2(acc) == exp(sim/T)
#define PRESCALE 4.539816004686735f

typedef __attribute__((ext_vector_type(4))) float f32x4;
typedef __attribute__((ext_vector_type(8))) short s16x8;

// ---------------- L2-normalize rows, scale, cast to bf16 (+ zero sums) -----
__global__ __launch_bounds__(256) void norm_kernel(const float* __restrict__ emb,
                                                   ushort* __restrict__ nbf,
                                                   float* __restrict__ sums) {
    // zero all_sum+pos_sum: 16384 floats over 256 blocks
    sums[blockIdx.x * 64 + (threadIdx.x >> 2)] = 0.0f;

    const int wave = threadIdx.x >> 6, lane = threadIdx.x & 63;
    for (int g = blockIdx.x; g < B_SZ / 4; g += 256) {
        const int row = g * 4 + wave;
        const float4 v = ((const float4*)(emb + (size_t)row * D_SZ))[lane];
        float ss = v.x * v.x + v.y * v.y + v.z * v.z + v.w * v.w;
        #pragma unroll
        for (int m = 1; m < 64; m <<= 1) ss += __shfl_xor(ss, m, 64);
        float s = PRESCALE / fmaxf(sqrtf(ss), 1e-12f);
        __hip_bfloat16 b0 = __float2bfloat16(v.x * s);
        __hip_bfloat16 b1 = __float2bfloat16(v.y * s);
        __hip_bfloat16 b2 = __float2bfloat16(v.z * s);
        __hip_bfloat16 b3 = __float2bfloat16(v.w * s);
        ushort4 o;
        o.x = *(ushort*)&b0; o.y = *(ushort*)&b1; o.z = *(ushort*)&b2; o.w = *(ushort*)&b3;
        ((ushort4*)(nbf + (size_t)row * D_SZ))[lane] = o;
    }
}

// ---------------- helpers ---------------------------------------------------
__device__ __forceinline__ void decode_tile(int tb, int& i0, int& j0, bool& diag) {
    int bj = (int)((sqrtf(8.0f * tb + 1.0f) - 1.0f) * 0.5f);
    while ((bj + 1) * (bj + 2) / 2 <= tb) ++bj;
    while (bj * (bj + 1) / 2 > tb) --bj;
    const int bi = tb - bj * (bj + 1) / 2;
    i0 = bi * 128; j0 = bj * 128; diag = (bi == bj);
}

// global -> VGPR, one BK=32 stage (128 rows x 64B per matrix, 2 int4/thread).
// Exact per-register vmcnt tracking; loads legally cross barriers (r17 win).
__device__ __forceinline__ void load32(int4 ra[2], int4 rb[2],
                                       const ushort* __restrict__ N,
                                       int i0, int j0, int ke,
                                       int wave, int lane) {
    const int rbase = wave * 16 + (lane >> 2);
    const int g     = lane & 3;              // global chunk16 within window
    #pragma unroll
    for (int h = 0; h < 2; ++h) {
        const int row = rbase + h * 64;
        ra[h] = *(const int4*)(N + (size_t)(i0 + row) * D_SZ + ke + g * 8);
        rb[h] = *(const int4*)(N + (size_t)(j0 + row) * D_SZ + ke + g * 8);
    }
}

// VGPR -> LDS; layout: slot s of row r holds global chunk16 s^((r>>1)&3)
// (write banks <=2-way, read banks <=2-way -- derived for 64B row stride).
__device__ __forceinline__ void store32(const int4 ra[2], const int4 rb[2],
                                        ushort* bufA, ushort* bufB,
                                        int wave, int lane) {
    const int rbase = wave * 16 + (lane >> 2);
    const int g     = lane & 3;
    #pragma unroll
    for (int h = 0; h < 2; ++h) {
        const int row = rbase + h * 64;
        const int s   = g ^ ((row >> 1) & 3);
        *(int4*)&bufA[row * 32 + s * 8] = ra[h];
        *(int4*)&bufB[row * 32 + s * 8] = rb[h];
    }
}

// one BK=32 k-step: 8 ds_read_b128 + 16 MFMAs
__device__ __forceinline__ void compute32(const ushort* bufA, const ushort* bufB,
                                          f32x4 acc[4][4], int wy, int wx, int lane) {
    const int c16 = lane >> 4;
    s16x8 af[4], bf[4];
    #pragma unroll
    for (int mi = 0; mi < 4; ++mi) {
        const int rr = wy * 64 + mi * 16 + (lane & 15);
        af[mi] = *(const s16x8*)&bufA[rr * 32 + (c16 ^ ((rr >> 1) & 3)) * 8];
    }
    #pragma unroll
    for (int ni = 0; ni < 4; ++ni) {
        const int rr = wx * 64 + ni * 16 + (lane & 15);
        bf[ni] = *(const s16x8*)&bufB[rr * 32 + (c16 ^ ((rr >> 1) & 3)) * 8];
    }
    #pragma unroll
    for (int mi = 0; mi < 4; ++mi)
        #pragma unroll
        for (int ni = 0; ni < 4; ++ni)
            acc[mi][ni] = __builtin_amdgcn_mfma_f32_16x16x32_bf16(
                af[mi], bf[ni], acc[mi][ni], 0, 0, 0);
}

// ---------------- fused sim: BK=32 VGPR-staged pipeline, depth-2 prefetch --
// Per stage kk: ds_write(set[kk&1], stage kk data loaded 2 stages ago; its
// vmcnt fully aged) -> issue loads for stage kk+2 into the freed set ->
// __syncthreads (lgkm only; loads stay in flight) -> ds_read + 16 MFMA.
// 32 KB dbuf LDS -> 4 blocks/CU. Epilogue barrier-free (shuffles + atomics);
// next tile's stage-0/1 loads age under it.
__global__ __launch_bounds__(256) void sim_kernel(const ushort* __restrict__ N,
                                                  const int* __restrict__ ids,
                                                  float* __restrict__ all_sum,
                                                  float* __restrict__ pos_sum) {
    __shared__ ushort smem[2 * 2 * 128 * 32];   // [buf][A|B][128 rows][32 ushorts]

    const int t    = threadIdx.x;
    const int wave = t >> 6, lane = t & 63;
    const int wy   = wave >> 1, wx = wave & 1;
    const int myc  = lane & 15;

    int tb = blockIdx.x;
    int i0, j0; bool diag;
    decode_tile(tb, i0, j0, diag);

    int4 ra[2][2], rb[2][2];                    // [set][h]
    load32(ra[0], rb[0], N, i0, j0, 0,  wave, lane);   // stage 0
    load32(ra[1], rb[1], N, i0, j0, 32, wave, lane);   // stage 1

    while (true) {
        const int ntb = tb + GRID_SIM;
        const bool have_next = (ntb < NTILES);
        int ni0 = i0, nj0 = j0; bool ndiag = diag;
        if (have_next) decode_tile(ntb, ni0, nj0, ndiag);

        f32x4 acc[4][4];
        #pragma unroll
        for (int mi = 0; mi < 4; ++mi)
            #pragma unroll
            for (int ni = 0; ni < 4; ++ni)
                acc[mi][ni] = (f32x4){0.f, 0.f, 0.f, 0.f};

        #pragma unroll
        for (int kk = 0; kk < 8; ++kk) {
            ushort* bufA = smem + (kk & 1) * 8192;
            ushort* bufB = bufA + 4096;
            const int s = kk & 1;
            store32(ra[s], rb[s], bufA, bufB, wave, lane);
            if (kk + 2 < 8)
                load32(ra[s], rb[s], N, i0, j0, (kk + 2) * 32, wave, lane);
            else if (have_next)
                load32(ra[s], rb[s], N, ni0, nj0, (kk + 2 - 8) * 32, wave, lane);
            __syncthreads();   // lgkm drain only; global loads stay in flight
            compute32(bufA, bufB, acc, wy, wx, lane);
            // WAR: buf (kk&1) rewritten at kk+2, after barrier kk+1 -- safe.
        }

        // ---- epilogue: barrier-free (registers + shuffles + atomics) ----
        // C/D map: col=lane&15, row=(lane>>4)*4+reg (tile-local via wy/wx)
        int idc[4];
        #pragma unroll
        for (int ni = 0; ni < 4; ++ni)
            idc[ni] = ids[j0 + wx * 64 + ni * 16 + myc];

        float cAll[4] = {0.f, 0.f, 0.f, 0.f};
        float cPos[4] = {0.f, 0.f, 0.f, 0.f};

        #pragma unroll
        for (int mi = 0; mi < 4; ++mi) {
            float rAll[4] = {0.f, 0.f, 0.f, 0.f};
            float rPos[4] = {0.f, 0.f, 0.f, 0.f};
            const int rbase = wy * 64 + mi * 16 + (lane >> 4) * 4;
            const int4 idr  = *(const int4*)&ids[i0 + rbase];
            #pragma unroll
            for (int ni = 0; ni < 4; ++ni) {
                const int cloc = wx * 64 + ni * 16 + myc;
                #pragma unroll
                for (int rg = 0; rg < 4; ++rg) {
                    float e = __builtin_amdgcn_exp2f(acc[mi][ni][rg]);
                    if (diag && (rbase + rg) == cloc) e = 0.0f;   // diagonal
                    rAll[rg] += e; cAll[ni] += e;
                    const int idrv = (rg == 0) ? idr.x : (rg == 1) ? idr.y
                                   : (rg == 2) ? idr.z : idr.w;
                    if (idrv == idc[ni]) { rPos[rg] += e; cPos[ni] += e; }
                }
            }
            #pragma unroll
            for (int rg = 0; rg < 4; ++rg) {
                #pragma unroll
                for (int mm = 1; mm < 16; mm <<= 1) {
                    rAll[rg] += __shfl_xor(rAll[rg], mm, 64);
                    rPos[rg] += __shfl_xor(rPos[rg], mm, 64);
                }
            }
            if (myc == 0) {
                #pragma unroll
                for (int rg = 0; rg < 4; ++rg) {
                    atomicAdd(&all_sum[i0 + rbase + rg], rAll[rg]);
                    if (rPos[rg] != 0.0f) atomicAdd(&pos_sum[i0 + rbase + rg], rPos[rg]);
                }
            }
        }

        // column sums -> rows j (off-diagonal tiles only; symmetry)
        if (!diag) {
            #pragma unroll
            for (int ni = 0; ni < 4; ++ni) {
                cAll[ni] += __shfl_xor(cAll[ni], 16, 64);
                cAll[ni] += __shfl_xor(cAll[ni], 32, 64);
                cPos[ni] += __shfl_xor(cPos[ni], 16, 64);
                cPos[ni] += __shfl_xor(cPos[ni], 32, 64);
            }
            if (lane < 16) {
                #pragma unroll
                for (int ni = 0; ni < 4; ++ni) {
                    const int gc = j0 + wx * 64 + ni * 16 + lane;
                    atomicAdd(&all_sum[gc], cAll[ni]);
                    if (cPos[ni] != 0.0f) atomicAdd(&pos_sum[gc], cPos[ni]);
                }
            }
        }

        if (!have_next) break;
        tb = ntb; i0 = ni0; j0 = nj0; diag = ndiag;
    }
}

// ---------------- final scalar reduce ----------------
__global__ __launch_bounds__(256) void loss_kernel(const float* __restrict__ all_sum,
                                                   const float* __restrict__ pos_sum,
                                                   float* __restrict__ out) {
    float loss = 0.0f, cnt = 0.0f;
    for (int i = threadIdx.x; i < B_SZ; i += 256) {
        float p = pos_sum[i], a = all_sum[i];
        if (p > 0.0f) { loss += logf(a) - logf(p); cnt += 1.0f; }
    }
    #pragma unroll
    for (int m = 1; m < 64; m <<= 1) {
        loss += __shfl_xor(loss, m, 64);
        cnt  += __shfl_xor(cnt, m, 64);
    }
    __shared__ float sl[4], sc[4];
    int wave = threadIdx.x >> 6, lane = threadIdx.x & 63;
    if (lane == 0) { sl[wave] = loss; sc[wave] = cnt; }
    __syncthreads();
    if (threadIdx.x == 0) {
        float L = sl[0] + sl[1] + sl[2] + sl[3];
        float C = sc[0] + sc[1] + sc[2] + sc[3];
        out[0] = L / fmaxf(C, 1.0f);
    }
}

extern "C" void kernel_launch(void* const* d_in, const int* in_sizes, int n_in,
                              void* d_out, int out_size, void* d_ws, size_t ws_size,
                              hipStream_t stream) {
    const float* emb = (const float*)d_in[0];
    const int*   ids = (const int*)d_in[1];
    float*       out = (float*)d_out;

    float*  all_sum = (float*)d_ws;
    float*  pos_sum = all_sum + B_SZ;
    ushort* nbf     = (ushort*)((char*)d_ws + 65536);   // 8192*256 bf16 = 4 MB

    norm_kernel<<<256, 256, 0, stream>>>(emb, nbf, all_sum);
    sim_kernel<<<GRID_SIM, 256, 0, stream>>>(nbf, ids, all_sum, pos_sum);
    loss_kernel<<<1, 256, 0, stream>>>(all_sum, pos_sum, out);
}

// Round 20
// 130.450 us; speedup vs baseline: 1.3979x; 1.3979x over previous
//
#include <hip/hip_runtime.h>
#include <hip/hip_bf16.h>

#define B_SZ 8192
#define D_SZ 256
#define NTILES 2080   // (8192/128)*(8192/128+1)/2 upper-tri tiles
#define GRID_SIM 1024 // persistent, 4 blocks/CU (32 KB LDS, ~112 VGPR)
// rows pre-scaled by sqrt(log2(e)/T): exp2(acc) == exp(sim/T)
#define PRESCALE 4.539816004686735f

typedef __attribute__((ext_vector_type(4))) float f32x4;
typedef __attribute__((ext_vector_type(8))) short s16x8;

// ---------------- L2-normalize rows, scale, cast to bf16 (+ zero sums) -----
__global__ __launch_bounds__(256) void norm_kernel(const float* __restrict__ emb,
                                                   ushort* __restrict__ nbf,
                                                   float* __restrict__ sums) {
    // zero all_sum+pos_sum: 16384 floats over 256 blocks
    sums[blockIdx.x * 64 + (threadIdx.x >> 2)] = 0.0f;

    const int wave = threadIdx.x >> 6, lane = threadIdx.x & 63;
    for (int g = blockIdx.x; g < B_SZ / 4; g += 256) {
        const int row = g * 4 + wave;
        const float4 v = ((const float4*)(emb + (size_t)row * D_SZ))[lane];
        float ss = v.x * v.x + v.y * v.y + v.z * v.z + v.w * v.w;
        #pragma unroll
        for (int m = 1; m < 64; m <<= 1) ss += __shfl_xor(ss, m, 64);
        float s = PRESCALE / fmaxf(sqrtf(ss), 1e-12f);
        __hip_bfloat16 b0 = __float2bfloat16(v.x * s);
        __hip_bfloat16 b1 = __float2bfloat16(v.y * s);
        __hip_bfloat16 b2 = __float2bfloat16(v.z * s);
        __hip_bfloat16 b3 = __float2bfloat16(v.w * s);
        ushort4 o;
        o.x = *(ushort*)&b0; o.y = *(ushort*)&b1; o.z = *(ushort*)&b2; o.w = *(ushort*)&b3;
        ((ushort4*)(nbf + (size_t)row * D_SZ))[lane] = o;
    }
}

// ---------------- helpers (r17 verbatim -- known non-spilling) --------------
__device__ __forceinline__ void decode_tile(int tb, int& i0, int& j0, bool& diag) {
    int bj = (int)((sqrtf(8.0f * tb + 1.0f) - 1.0f) * 0.5f);
    while ((bj + 1) * (bj + 2) / 2 <= tb) ++bj;
    while (bj * (bj + 1) / 2 > tb) --bj;
    const int bi = tb - bj * (bj + 1) / 2;
    i0 = bi * 128; j0 = bj * 128; diag = (bi == bj);
}

// global -> VGPR staging (exact vmcnt tracking; loads may cross barriers).
__device__ __forceinline__ void load_regs(s16x8 ra[4], s16x8 rb[4],
                                          const ushort* __restrict__ N,
                                          int i0, int j0, int k0,
                                          int wave, int r, int c8s) {
    const ushort* gA = N + (size_t)(i0 + wave * 32) * D_SZ + k0;
    const ushort* gB = N + (size_t)(j0 + wave * 32) * D_SZ + k0;
    #pragma unroll
    for (int q = 0; q < 4; ++q) {
        ra[q] = *(const s16x8*)(gA + (size_t)(q * 8 + r) * D_SZ + c8s);
        rb[q] = *(const s16x8*)(gB + (size_t)(q * 8 + r) * D_SZ + c8s);
    }
}

// VGPR -> LDS: row wave*32+q*8+(lane>>3), slot lane&7 holds chunk (lane&7)^r.
__device__ __forceinline__ void store_stage(const s16x8 ra[4], const s16x8 rb[4],
                                            ushort* bA, ushort* bB,
                                            int wave, int lane) {
    #pragma unroll
    for (int q = 0; q < 4; ++q) {
        *(s16x8*)&bA[(wave * 32 + q * 8) * 64 + lane * 8] = ra[q];
        *(s16x8*)&bB[(wave * 32 + q * 8) * 64 + lane * 8] = rb[q];
    }
}

// ---------------- fused sim: single-buffer VGPR-staged pipeline ------------
// Per stage: top barrier (prior reads done; lgkm-only) -> ds_write(regs,
// vmcnt aged one full stage) -> issue loads k+1 -> barrier (lgkm-only;
// NEW GLOBAL LOADS STAY IN FLIGHT -- the r17 mechanism) -> ds_read + MFMA.
// Single 32 KB buffer -> 4 blocks/CU (2x r17 residency). Epilogue barrier-
// free (registers + shuffles + atomics); next tile's loads age under it.
__global__ __launch_bounds__(256) void sim_kernel(const ushort* __restrict__ N,
                                                  const int* __restrict__ ids,
                                                  float* __restrict__ all_sum,
                                                  float* __restrict__ pos_sum) {
    __shared__ ushort sA[128 * 64];   // 16 KB
    __shared__ ushort sB[128 * 64];   // 16 KB

    const int t    = threadIdx.x;
    const int wave = t >> 6, lane = t & 63;
    const int wy   = wave >> 1, wx = wave & 1;
    const int r    = lane >> 3;                     // 0..7 sub-row
    const int c8s  = ((lane & 7) ^ r) * 8;          // swizzled source chunk
    const int myc  = lane & 15;

    int tb = blockIdx.x;
    int i0, j0; bool diag;
    decode_tile(tb, i0, j0, diag);

    s16x8 ra[4], rb[4];
    load_regs(ra, rb, N, i0, j0, 0, wave, r, c8s);

    while (true) {
        const int ntb = tb + GRID_SIM;
        const bool have_next = (ntb < NTILES);
        int ni0 = i0, nj0 = j0; bool ndiag = diag;
        if (have_next) decode_tile(ntb, ni0, nj0, ndiag);

        f32x4 acc[4][4];
        #pragma unroll
        for (int mi = 0; mi < 4; ++mi)
            #pragma unroll
            for (int ni = 0; ni < 4; ++ni)
                acc[mi][ni] = (f32x4){0.f, 0.f, 0.f, 0.f};

        #pragma unroll
        for (int kk = 0; kk < 4; ++kk) {
            __syncthreads();      // prior stage's reads complete (lgkm-only)
            store_stage(ra, rb, sA, sB, wave, lane);
            if (kk < 3)           load_regs(ra, rb, N, i0, j0, (kk + 1) * 64, wave, r, c8s);
            else if (have_next)   load_regs(ra, rb, N, ni0, nj0, 0, wave, r, c8s);
            __syncthreads();      // writes visible; new loads stay in flight

            #pragma unroll
            for (int ks = 0; ks < 2; ++ks) {
                const int C = ks * 4 + (lane >> 4);     // k-chunk index 0..7
                const int slot = (C ^ (lane & 7)) * 8;  // un-swizzle
                s16x8 af[4], bf[4];
                #pragma unroll
                for (int mi = 0; mi < 4; ++mi)
                    af[mi] = *(const s16x8*)&sA[(wy * 64 + mi * 16 + (lane & 15)) * 64 + slot];
                #pragma unroll
                for (int ni = 0; ni < 4; ++ni)
                    bf[ni] = *(const s16x8*)&sB[(wx * 64 + ni * 16 + (lane & 15)) * 64 + slot];
                #pragma unroll
                for (int mi = 0; mi < 4; ++mi)
                    #pragma unroll
                    for (int ni = 0; ni < 4; ++ni)
                        acc[mi][ni] = __builtin_amdgcn_mfma_f32_16x16x32_bf16(
                            af[mi], bf[ni], acc[mi][ni], 0, 0, 0);
            }
            // WAR: next store happens after next iteration's top barrier.
        }

        // ---- epilogue: barrier-free (registers + shuffles + atomics) ----
        // C/D map: col=lane&15, row=(lane>>4)*4+reg
        int idc[4];
        #pragma unroll
        for (int ni = 0; ni < 4; ++ni)
            idc[ni] = ids[j0 + wx * 64 + ni * 16 + myc];

        float cAll[4] = {0.f, 0.f, 0.f, 0.f};
        float cPos[4] = {0.f, 0.f, 0.f, 0.f};

        #pragma unroll
        for (int mi = 0; mi < 4; ++mi) {
            float rAll[4] = {0.f, 0.f, 0.f, 0.f};
            float rPos[4] = {0.f, 0.f, 0.f, 0.f};
            const int rbase = wy * 64 + mi * 16 + (lane >> 4) * 4;
            const int4 idr  = *(const int4*)&ids[i0 + rbase];
            #pragma unroll
            for (int ni = 0; ni < 4; ++ni) {
                const int cloc = wx * 64 + ni * 16 + myc;
                #pragma unroll
                for (int rg = 0; rg < 4; ++rg) {
                    float e = __builtin_amdgcn_exp2f(acc[mi][ni][rg]);
                    if (diag && (rbase + rg) == cloc) e = 0.0f;   // diagonal
                    rAll[rg] += e; cAll[ni] += e;
                    const int idrv = (rg == 0) ? idr.x : (rg == 1) ? idr.y
                                   : (rg == 2) ? idr.z : idr.w;
                    if (idrv == idc[ni]) { rPos[rg] += e; cPos[ni] += e; }
                }
            }
            #pragma unroll
            for (int rg = 0; rg < 4; ++rg) {
                #pragma unroll
                for (int mm = 1; mm < 16; mm <<= 1) {
                    rAll[rg] += __shfl_xor(rAll[rg], mm, 64);
                    rPos[rg] += __shfl_xor(rPos[rg], mm, 64);
                }
            }
            if (myc == 0) {
                #pragma unroll
                for (int rg = 0; rg < 4; ++rg) {
                    atomicAdd(&all_sum[i0 + rbase + rg], rAll[rg]);
                    if (rPos[rg] != 0.0f) atomicAdd(&pos_sum[i0 + rbase + rg], rPos[rg]);
                }
            }
        }

        // column sums -> rows j (off-diagonal tiles only; symmetry)
        if (!diag) {
            #pragma unroll
            for (int ni = 0; ni < 4; ++ni) {
                cAll[ni] += __shfl_xor(cAll[ni], 16, 64);
                cAll[ni] += __shfl_xor(cAll[ni], 32, 64);
                cPos[ni] += __shfl_xor(cPos[ni], 16, 64);
                cPos[ni] += __shfl_xor(cPos[ni], 32, 64);
            }
            if (lane < 16) {
                #pragma unroll
                for (int ni = 0; ni < 4; ++ni) {
                    const int gc = j0 + wx * 64 + ni * 16 + lane;
                    atomicAdd(&all_sum[gc], cAll[ni]);
                    if (cPos[ni] != 0.0f) atomicAdd(&pos_sum[gc], cPos[ni]);
                }
            }
        }

        if (!have_next) break;
        tb = ntb; i0 = ni0; j0 = nj0; diag = ndiag;
    }
}

// ---------------- final scalar reduce ----------------
__global__ __launch_bounds__(256) void loss_kernel(const float* __restrict__ all_sum,
                                                   const float* __restrict__ pos_sum,
                                                   float* __restrict__ out) {
    float loss = 0.0f, cnt = 0.0f;
    for (int i = threadIdx.x; i < B_SZ; i += 256) {
        float p = pos_sum[i], a = all_sum[i];
        if (p > 0.0f) { loss += logf(a) - logf(p); cnt += 1.0f; }
    }
    #pragma unroll
    for (int m = 1; m < 64; m <<= 1) {
        loss += __shfl_xor(loss, m, 64);
        cnt  += __shfl_xor(cnt, m, 64);
    }
    __shared__ float sl[4], sc[4];
    int wave = threadIdx.x >> 6, lane = threadIdx.x & 63;
    if (lane == 0) { sl[wave] = loss; sc[wave] = cnt; }
    __syncthreads();
    if (threadIdx.x == 0) {
        float L = sl[0] + sl[1] + sl[2] + sl[3];
        float C = sc[0] + sc[1] + sc[2] + sc[3];
        out[0] = L / fmaxf(C, 1.0f);
    }
}

extern "C" void kernel_launch(void* const* d_in, const int* in_sizes, int n_in,
                              void* d_out, int out_size, void* d_ws, size_t ws_size,
                              hipStream_t stream) {
    const float* emb = (const float*)d_in[0];
    const int*   ids = (const int*)d_in[1];
    float*       out = (float*)d_out;

    float*  all_sum = (float*)d_ws;
    float*  pos_sum = all_sum + B_SZ;
    ushort* nbf     = (ushort*)((char*)d_ws + 65536);   // 8192*256 bf16 = 4 MB

    norm_kernel<<<256, 256, 0, stream>>>(emb, nbf, all_sum);
    sim_kernel<<<GRID_SIM, 256, 0, stream>>>(nbf, ids, all_sum, pos_sum);
    loss_kernel<<<1, 256, 0, stream>>>(all_sum, pos_sum, out);
}

// Round 21
// 116.979 us; speedup vs baseline: 1.5589x; 1.1152x over previous
//
#include <hip/hip_runtime.h>
#include <hip/hip_bf16.h>

#define B_SZ 8192
#define D_SZ 256
#define NTILES 2080   // (8192/128)*(8192/128+1)/2 upper-tri tiles
#define GRID_SIM 512  // persistent, 2 blocks/CU (64 KB LDS)
// rows pre-scaled by sqrt(log2(e)/T): exp2(acc) == exp(sim/T)
#define PRESCALE 4.539816004686735f

typedef __attribute__((ext_vector_type(4))) float f32x4;
typedef __attribute__((ext_vector_type(8))) short s16x8;

// ---------------- L2-normalize rows, scale, cast to bf16 (+ zero sums) -----
__global__ __launch_bounds__(256) void norm_kernel(const float* __restrict__ emb,
                                                   ushort* __restrict__ nbf,
                                                   float* __restrict__ sums) {
    // zero all_sum+pos_sum: 16384 floats over 256 blocks
    sums[blockIdx.x * 64 + (threadIdx.x >> 2)] = 0.0f;

    const int wave = threadIdx.x >> 6, lane = threadIdx.x & 63;
    for (int g = blockIdx.x; g < B_SZ / 4; g += 256) {
        const int row = g * 4 + wave;
        const float4 v = ((const float4*)(emb + (size_t)row * D_SZ))[lane];
        float ss = v.x * v.x + v.y * v.y + v.z * v.z + v.w * v.w;
        #pragma unroll
        for (int m = 1; m < 64; m <<= 1) ss += __shfl_xor(ss, m, 64);
        float s = PRESCALE / fmaxf(sqrtf(ss), 1e-12f);
        __hip_bfloat16 b0 = __float2bfloat16(v.x * s);
        __hip_bfloat16 b1 = __float2bfloat16(v.y * s);
        __hip_bfloat16 b2 = __float2bfloat16(v.z * s);
        __hip_bfloat16 b3 = __float2bfloat16(v.w * s);
        ushort4 o;
        o.x = *(ushort*)&b0; o.y = *(ushort*)&b1; o.z = *(ushort*)&b2; o.w = *(ushort*)&b3;
        ((ushort4*)(nbf + (size_t)row * D_SZ))[lane] = o;
    }
}

// ---------------- helpers ---------------------------------------------------
__device__ __forceinline__ void decode_tile(int tb, int& i0, int& j0, bool& diag) {
    int bj = (int)((sqrtf(8.0f * tb + 1.0f) - 1.0f) * 0.5f);
    while ((bj + 1) * (bj + 2) / 2 <= tb) ++bj;
    while (bj * (bj + 1) / 2 > tb) --bj;
    const int bi = tb - bj * (bj + 1) / 2;
    i0 = bi * 128; j0 = bj * 128; diag = (bi == bj);
}

// global -> VGPR staging (exact vmcnt tracking; loads may cross barriers).
// Lane pattern identical to the old DMA (row q*8+r, swizzled chunk c8s).
__device__ __forceinline__ void load_regs(s16x8 ra[4], s16x8 rb[4],
                                          const ushort* __restrict__ N,
                                          int i0, int j0, int k0,
                                          int wave, int r, int c8s) {
    const ushort* gA = N + (size_t)(i0 + wave * 32) * D_SZ + k0;
    const ushort* gB = N + (size_t)(j0 + wave * 32) * D_SZ + k0;
    #pragma unroll
    for (int q = 0; q < 4; ++q) {
        ra[q] = *(const s16x8*)(gA + (size_t)(q * 8 + r) * D_SZ + c8s);
        rb[q] = *(const s16x8*)(gB + (size_t)(q * 8 + r) * D_SZ + c8s);
    }
}

// VGPR -> LDS: lane writes its 16B at base + lane*16 (matches DMA layout:
// LDS row wave*32+q*8+(lane>>3), slot lane&7 holds source chunk (lane&7)^r).
__device__ __forceinline__ void store_stage(const s16x8 ra[4], const s16x8 rb[4],
                                            ushort* bA, ushort* bB,
                                            int wave, int lane) {
    #pragma unroll
    for (int q = 0; q < 4; ++q) {
        *(s16x8*)&bA[(wave * 32 + q * 8) * 64 + lane * 8] = ra[q];
        *(s16x8*)&bB[(wave * 32 + q * 8) * 64 + lane * 8] = rb[q];
    }
}

// ---------------- fused sim: VGPR-staged pipeline, persistent tiles --------
// Per stage: ds_write(regs k) [waits aged vmcnt] -> issue loads k+1 ->
// __syncthreads [lgkm only -- loads stay IN FLIGHT across the barrier] ->
// ds_read + MFMA. Double-buffered LDS (64 KB); buffer parity makes one
// barrier per stage sufficient. Epilogue = r11 (partials in buf0 region).
__global__ __launch_bounds__(256) void sim_kernel(const ushort* __restrict__ N,
                                                  const int* __restrict__ ids,
                                                  float* __restrict__ all_sum,
                                                  float* __restrict__ pos_sum) {
    __shared__ ushort smem[4 * 128 * 64];   // A0|B0|A1|B1, 16 KB each

    const int t    = threadIdx.x;
    const int wave = t >> 6, lane = t & 63;
    const int wy   = wave >> 1, wx = wave & 1;
    const int r    = lane >> 3;                     // 0..7 sub-row
    const int c8s  = ((lane & 7) ^ r) * 8;          // swizzled source chunk
    const int myc  = lane & 15;

    int tb = blockIdx.x;
    int i0, j0; bool diag;
    decode_tile(tb, i0, j0, diag);

    s16x8 ra[4], rb[4];
    load_regs(ra, rb, N, i0, j0, 0, wave, r, c8s);

    while (true) {
        const int ntb = tb + GRID_SIM;
        const bool have_next = (ntb < NTILES);
        int ni0 = i0, nj0 = j0; bool ndiag = diag;
        if (have_next) decode_tile(ntb, ni0, nj0, ndiag);

        f32x4 acc[4][4];
        #pragma unroll
        for (int mi = 0; mi < 4; ++mi)
            #pragma unroll
            for (int ni = 0; ni < 4; ++ni)
                acc[mi][ni] = (f32x4){0.f, 0.f, 0.f, 0.f};

        #pragma unroll
        for (int kk = 0; kk < 4; ++kk) {
            ushort* bA = smem + (kk & 1) * 16384;   // 2*128*64 ushorts = 16384
            ushort* bB = bA + 8192;
            store_stage(ra, rb, bA, bB, wave, lane);
            if (kk < 3)           load_regs(ra, rb, N, i0, j0, (kk + 1) * 64, wave, r, c8s);
            else if (have_next)   load_regs(ra, rb, N, ni0, nj0, 0, wave, r, c8s);
            __syncthreads();      // lgkm drain; new global loads stay in flight

            #pragma unroll
            for (int ks = 0; ks < 2; ++ks) {
                const int C = ks * 4 + (lane >> 4);     // k-chunk index 0..7
                const int slot = (C ^ (lane & 7)) * 8;  // un-swizzle
                s16x8 af[4], bf[4];
                #pragma unroll
                for (int mi = 0; mi < 4; ++mi)
                    af[mi] = *(const s16x8*)&bA[(wy * 64 + mi * 16 + (lane & 15)) * 64 + slot];
                #pragma unroll
                for (int ni = 0; ni < 4; ++ni)
                    bf[ni] = *(const s16x8*)&bB[(wx * 64 + ni * 16 + (lane & 15)) * 64 + slot];
                #pragma unroll
                for (int mi = 0; mi < 4; ++mi)
                    #pragma unroll
                    for (int ni = 0; ni < 4; ++ni)
                        acc[mi][ni] = __builtin_amdgcn_mfma_f32_16x16x32_bf16(
                            af[mi], bf[ni], acc[mi][ni], 0, 0, 0);
            }
            // WAR safety: buf (kk&1) is next written at stage kk+2, which is
            // after barrier kk+1 -- all waves' reads of it are complete then.
        }

        // ---- epilogue (r11).  C/D map: col=lane&15, row=(lane>>4)*4+reg ----
        // Partials live in buf0 region (A0=rowAll, B0=rowPos): buf0 was last
        // read at stage kk=2; barrier kk=3 separates -> safe.
        float* rowAllPart = (float*)smem;            // [128][32]
        float* rowPosPart = (float*)&smem[8192];     // [128][32]

        int idc[4];
        #pragma unroll
        for (int ni = 0; ni < 4; ++ni)
            idc[ni] = ids[j0 + wx * 64 + ni * 16 + myc];

        float cAll[4] = {0.f, 0.f, 0.f, 0.f};
        float cPos[4] = {0.f, 0.f, 0.f, 0.f};

        #pragma unroll
        for (int mi = 0; mi < 4; ++mi) {
            float rAll[4] = {0.f, 0.f, 0.f, 0.f};
            float rPos[4] = {0.f, 0.f, 0.f, 0.f};
            const int rbase = wy * 64 + mi * 16 + (lane >> 4) * 4;
            const int4 idr  = *(const int4*)&ids[i0 + rbase];
            #pragma unroll
            for (int ni = 0; ni < 4; ++ni) {
                const int cloc = wx * 64 + ni * 16 + myc;
                #pragma unroll
                for (int rg = 0; rg < 4; ++rg) {
                    const int lr = rbase + rg;
                    float e = __builtin_amdgcn_exp2f(acc[mi][ni][rg]);
                    if (diag && lr == cloc) e = 0.0f;        // diagonal element
                    rAll[rg] += e; cAll[ni] += e;
                    const int idrv = (rg == 0) ? idr.x : (rg == 1) ? idr.y
                                   : (rg == 2) ? idr.z : idr.w;
                    if (idrv == idc[ni]) { rPos[rg] += e; cPos[ni] += e; }
                }
            }
            #pragma unroll
            for (int rg = 0; rg < 4; ++rg) {
                rowAllPart[(rbase + rg) * 32 + wx * 16 + myc] = rAll[rg];
                rowPosPart[(rbase + rg) * 32 + wx * 16 + myc] = rPos[rg];
            }
        }

        // column sums -> rows j (off-diagonal tiles only; symmetry)
        if (!diag) {
            #pragma unroll
            for (int ni = 0; ni < 4; ++ni) {
                cAll[ni] += __shfl_xor(cAll[ni], 16, 64);
                cAll[ni] += __shfl_xor(cAll[ni], 32, 64);
                cPos[ni] += __shfl_xor(cPos[ni], 16, 64);
                cPos[ni] += __shfl_xor(cPos[ni], 32, 64);
            }
            if (lane < 16) {
                #pragma unroll
                for (int ni = 0; ni < 4; ++ni) {
                    const int gc = j0 + wx * 64 + ni * 16 + lane;
                    atomicAdd(&all_sum[gc], cAll[ni]);
                    if (cPos[ni] != 0.0f) atomicAdd(&pos_sum[gc], cPos[ni]);
                }
            }
        }

        __syncthreads();
        // row partial reduce: thread t -> (row = t&127, array = t>>7)
        {
            const int row = t & 127;
            const float* src = (t >= 128) ? rowPosPart : rowAllPart;
            float s = 0.0f;
            #pragma unroll
            for (int k8 = 0; k8 < 8; ++k8) {
                const int chunk = (k8 + (row & 7)) & 7;
                const float4 v = *(const float4*)&src[row * 32 + chunk * 4];
                s += v.x + v.y + v.z + v.w;
            }
            float* dst = (t >= 128) ? pos_sum : all_sum;
            atomicAdd(&dst[i0 + row], s);
        }
        __syncthreads();   // partials consumed; buf0 reusable next tile

        if (!have_next) break;
        tb = ntb; i0 = ni0; j0 = nj0; diag = ndiag;
    }
}

// ---------------- final scalar reduce ----------------
__global__ __launch_bounds__(256) void loss_kernel(const float* __restrict__ all_sum,
                                                   const float* __restrict__ pos_sum,
                                                   float* __restrict__ out) {
    float loss = 0.0f, cnt = 0.0f;
    for (int i = threadIdx.x; i < B_SZ; i += 256) {
        float p = pos_sum[i], a = all_sum[i];
        if (p > 0.0f) { loss += logf(a) - logf(p); cnt += 1.0f; }
    }
    #pragma unroll
    for (int m = 1; m < 64; m <<= 1) {
        loss += __shfl_xor(loss, m, 64);
        cnt  += __shfl_xor(cnt, m, 64);
    }
    __shared__ float sl[4], sc[4];
    int wave = threadIdx.x >> 6, lane = threadIdx.x & 63;
    if (lane == 0) { sl[wave] = loss; sc[wave] = cnt; }
    __syncthreads();
    if (threadIdx.x == 0) {
        float L = sl[0] + sl[1] + sl[2] + sl[3];
        float C = sc[0] + sc[1] + sc[2] + sc[3];
        out[0] = L / fmaxf(C, 1.0f);
    }
}

extern "C" void kernel_launch(void* const* d_in, const int* in_sizes, int n_in,
                              void* d_out, int out_size, void* d_ws, size_t ws_size,
                              hipStream_t stream) {
    const float* emb = (const float*)d_in[0];
    const int*   ids = (const int*)d_in[1];
    float*       out = (float*)d_out;

    float*  all_sum = (float*)d_ws;
    float*  pos_sum = all_sum + B_SZ;
    ushort* nbf     = (ushort*)((char*)d_ws + 65536);   // 8192*256 bf16 = 4 MB

    norm_kernel<<<256, 256, 0, stream>>>(emb, nbf, all_sum);
    sim_kernel<<<GRID_SIM, 256, 0, stream>>>(nbf, ids, all_sum, pos_sum);
    loss_kernel<<<1, 256, 0, stream>>>(all_sum, pos_sum, out);
}